// Round 1
// baseline (189.243 us; speedup 1.0000x reference)
//
#include <hip/hip_runtime.h>
#include <math.h>

#define C_CH 256
#define RESO 7
#define NBIN 49   // 7*7
#define CHALF 128 // channels per gather block

typedef float fx4 __attribute__((ext_vector_type(4)));
typedef unsigned int ux2 __attribute__((ext_vector_type(2)));

// f32 -> bf16, round-to-nearest-even
__device__ __forceinline__ unsigned short f2bf(float f) {
  unsigned int u = __float_as_uint(f);
  u = (u + 0x7fffu + ((u >> 16) & 1u)) >> 16;
  return (unsigned short)u;
}
__device__ __forceinline__ float bf_lo(unsigned int u) { return __uint_as_float(u << 16); }
__device__ __forceinline__ float bf_hi(unsigned int u) { return __uint_as_float(u & 0xffff0000u); }

// ---------------------------------------------------------------------------
// Merged NCHW(f32) -> NHWC(bf16), all 4 levels, ONE persistent dispatch.
// 2048 blocks x 256 thr, grid-stride over 64c x 64hw tiles, software
// pipeline: tile k+1's 4 float4 loads are issued before the barrier that
// precedes tile k's LDS-read/pack/store phase, so global loads stay in
// flight through the whole store phase (register double-buffer).
// (unchanged this round — measured near its streaming roofline)
// ---------------------------------------------------------------------------
struct TArgs {
  const float* src[4];
  unsigned short* dst[4];
  int hw[4];
  int tilesx[4];  // ceil(hw/64)
  int tbase[5];   // cumulative tiles per level (tilesx*4*2)
  int total;
};

__device__ __forceinline__ void decode_tile(const TArgs& a, int T, int& l, int& hw0,
                                            int& c0, int& n, int& HW) {
  int ll = 0;
  if (T >= a.tbase[1]) ll = 1;
  if (T >= a.tbase[2]) ll = 2;
  if (T >= a.tbase[3]) ll = 3;
  const int idx = T - a.tbase[ll];
  const int txs = a.tilesx[ll];
  const int tx = idx % txs;
  const int rem = idx / txs;
  l = ll;
  hw0 = tx * 64;
  c0 = (rem & 3) * 64;
  n = rem >> 2;
  HW = a.hw[ll];
}

__device__ __forceinline__ void load_tile(const TArgs& a, int l, int hw0, int c0, int n,
                                          int HW, int lane16, int row16, fx4 v[4]) {
  const float* s = a.src[l] + (size_t)n * C_CH * HW;
  if (((HW & 3) == 0) && (hw0 + 64 <= HW)) {
#pragma unroll
    for (int i = 0; i < 4; ++i) {
      const int c_l = row16 + 16 * i;
      v[i] = __builtin_nontemporal_load(
          (const fx4*)(s + (size_t)(c0 + c_l) * HW + hw0 + lane16 * 4));
    }
  } else {
#pragma unroll
    for (int i = 0; i < 4; ++i) {
      const int c_l = row16 + 16 * i;
      const float* row = s + (size_t)(c0 + c_l) * HW;
#pragma unroll
      for (int k = 0; k < 4; ++k) {
        const int hw = hw0 + lane16 * 4 + k;
        v[i][k] = (hw < HW) ? row[hw] : 0.0f;
      }
    }
  }
}

__global__ __launch_bounds__(256) void conv_nhwc_bf16(TArgs a) {
  __shared__ float tile[64][65];
  const int t = threadIdx.x;
  const int lane16 = t & 15;
  const int row16 = t >> 4;
  const int stride = gridDim.x;

  int T = blockIdx.x;
  int l0, hw00, c00, n0, HW0;
  decode_tile(a, T, l0, hw00, c00, n0, HW0);
  fx4 v[4];
  load_tile(a, l0, hw00, c00, n0, HW0, lane16, row16, v);

  while (true) {
    __syncthreads();  // previous store phase done reading LDS
#pragma unroll
    for (int i = 0; i < 4; ++i) {
      const int c_l = row16 + 16 * i;
      tile[c_l][lane16 * 4 + 0] = v[i][0];
      tile[c_l][lane16 * 4 + 1] = v[i][1];
      tile[c_l][lane16 * 4 + 2] = v[i][2];
      tile[c_l][lane16 * 4 + 3] = v[i][3];
    }

    // prefetch next tile BEFORE the barrier -> loads overlap store phase
    const int Tn = T + stride;
    const bool more = Tn < a.total;
    int l1, hw01, c01, n1, HW1;
    fx4 w[4];
    if (more) {
      decode_tile(a, Tn, l1, hw01, c01, n1, HW1);
      load_tile(a, l1, hw01, c01, n1, HW1, lane16, row16, w);
    }
    __syncthreads();

    // store phase for tile T
    unsigned short* d = a.dst[l0] + (size_t)n0 * HW0 * C_CH;
#pragma unroll
    for (int i = 0; i < 4; ++i) {
      const int hw_l = row16 + 16 * i;
      const int hww = hw00 + hw_l;
      if (hww < HW0) {
        const int c4 = lane16 * 4;
        ux2 p;
        p.x = (unsigned int)f2bf(tile[c4 + 0][hw_l]) |
              ((unsigned int)f2bf(tile[c4 + 1][hw_l]) << 16);
        p.y = (unsigned int)f2bf(tile[c4 + 2][hw_l]) |
              ((unsigned int)f2bf(tile[c4 + 3][hw_l]) << 16);
        *(ux2*)(d + (size_t)hww * C_CH + c00 + c4) = p;
      }
    }

    if (!more) break;
    T = Tn;
    l0 = l1; hw00 = hw01; c00 = c01; n0 = n1; HW0 = HW1;
#pragma unroll
    for (int i = 0; i < 4; ++i) v[i] = w[i];
  }
}

// ---------------------------------------------------------------------------
// RoIAlign gather, bf16 NHWC.  2048 blocks: block = (ROI, channel-half).
// obuf is 128ch*49bins = 25KB -> wave-limited occupancy: 4 blocks/CU =
// 32 waves/CU (was 3 blocks/CU, LDS-limited, with a 256-block tail).
// Lane split: cg=ln&15 (8 channels, one uint4 tap), xt=bit4, yt=bit5 ->
// each lane loads ONE 16B tap per (s1,s2) sample; two shfl_xor (16,32)
// combine the 2x2 bilinear quadrants.  __launch_bounds__(512,8) pins
// VGPR<=64 so all 8 waves/SIMD are resident.
// ---------------------------------------------------------------------------
__global__ __launch_bounds__(512, 8) void roi_gather_bf16(
    const unsigned short* __restrict__ f0, const unsigned short* __restrict__ f1,
    const unsigned short* __restrict__ f2, const unsigned short* __restrict__ f3,
    const float* __restrict__ props0, const float* __restrict__ props1,
    float* __restrict__ out) {
  __shared__ float obuf[CHALF * NBIN];      // c-major: obuf[c_local*49 + bin]
  __shared__ int s_o0[2][14], s_o1[2][14];  // pre-scaled lo/hi offsets (0=y,1=x)
  __shared__ float s_w0[2][14], s_w1[2][14];

  const int bid = blockIdx.x;
  const int r = bid >> 1;   // ROI index 0..1023
  const int p = bid & 1;    // channel half 0..1
  const int t = threadIdx.x;
  const int b = (r >= 512) ? 1 : 0;
  const float* pr = (b ? props1 : props0) + (r & 511) * 4;
  const float x1 = pr[0], y1 = pr[1], x2 = pr[2], y2 = pr[3];

  // level assignment (match numpy f32 math exactly)
  const float size = sqrtf((x2 - x1 + 1.0f) * (y2 - y1 + 1.0f));
  float lv = floorf(4.0f + log2f(size / 224.0f + 1e-6f));
  lv = fminf(fmaxf(lv, 2.0f), 5.0f) - 2.0f;
  const int lvl = (int)lv;

  const int Htab[4] = {200, 100, 50, 25};
  const float stab[4] = {0.25f, 0.125f, 0.0625f, 0.03125f};
  const int H = Htab[lvl];
  const int W = H;
  const float sc = stab[lvl];
  const unsigned short* fl = (lvl == 0) ? f0 : (lvl == 1) ? f1 : (lvl == 2) ? f2 : f3;

  const float rx1 = x1 * sc, ry1 = y1 * sc;
  const float roi_w = fmaxf(x2 * sc - rx1, 1.0f);
  const float roi_h = fmaxf(y2 * sc - ry1, 1.0f);
  const float bw = roi_w / 7.0f, bh = roi_h / 7.0f;

  if (t < 28) {
    const int axis = t / 14;  // 0 = y, 1 = x
    const int k = t % 14;
    const float off = ((float)k + 0.5f) * 0.5f;
    const float v = axis ? (rx1 + off * bw) : (ry1 + off * bh);
    const int isz = H;
    const bool valid = (v >= -1.0f) && (v <= (float)isz);
    const float v0 = fmaxf(v, 0.0f);
    int lo = (int)floorf(v0);
    const bool edge = (lo >= isz - 1);
    lo = edge ? isz - 1 : lo;
    const int hi = edge ? isz - 1 : lo + 1;
    const float fr = edge ? 0.0f : (v0 - (float)lo);
    const int mul = axis ? C_CH : W * C_CH;
    // fold the 2x2-sample mean (0.25) into the y-axis weights
    const float wsc = axis ? 1.0f : 0.25f;
    s_o0[axis][k] = lo * mul;
    s_o1[axis][k] = hi * mul;
    s_w1[axis][k] = valid ? fr * wsc : 0.0f;
    s_w0[axis][k] = valid ? (1.0f - fr) * wsc : 0.0f;
  }
  __syncthreads();

  const int wv = t >> 6;     // wave 0..7: splits bins
  const int ln = t & 63;
  const int cg = ln & 15;    // channel group of 8 (within this 128-ch half)
  const int sub = ln >> 4;   // bit0 = xt, bit1 = yt
  const int xt = sub & 1;
  const int yt = sub >> 1;
  const size_t HWp = (size_t)H * W;
  const unsigned short* base = fl + (size_t)b * HWp * C_CH + p * CHALF + cg * 8;

  for (int bb = wv; bb < NBIN; bb += 8) {
    const int ph = bb / 7, pw = bb - ph * 7;
    float acc[8] = {0.f, 0.f, 0.f, 0.f, 0.f, 0.f, 0.f, 0.f};
#pragma unroll
    for (int s1 = 0; s1 < 2; ++s1) {
      const int sy = 2 * ph + s1;
      const int yo = yt ? s_o1[0][sy] : s_o0[0][sy];
      const float wy = yt ? s_w1[0][sy] : s_w0[0][sy];
#pragma unroll
      for (int s2 = 0; s2 < 2; ++s2) {
        const int sx = 2 * pw + s2;
        const int xo = xt ? s_o1[1][sx] : s_o0[1][sx];
        const float wx = xt ? s_w1[1][sx] : s_w0[1][sx];
        const uint4 q = *(const uint4*)(base + yo + xo);
        const float w = wy * wx;
        acc[0] = fmaf(bf_lo(q.x), w, acc[0]);
        acc[1] = fmaf(bf_hi(q.x), w, acc[1]);
        acc[2] = fmaf(bf_lo(q.y), w, acc[2]);
        acc[3] = fmaf(bf_hi(q.y), w, acc[3]);
        acc[4] = fmaf(bf_lo(q.z), w, acc[4]);
        acc[5] = fmaf(bf_hi(q.z), w, acc[5]);
        acc[6] = fmaf(bf_lo(q.w), w, acc[6]);
        acc[7] = fmaf(bf_hi(q.w), w, acc[7]);
      }
    }
    // combine the 2x2 bilinear quadrants spread across lanes (bit4=xt, bit5=yt)
#pragma unroll
    for (int k = 0; k < 8; ++k) {
      acc[k] += __shfl_xor(acc[k], 16);
      acc[k] += __shfl_xor(acc[k], 32);
    }
    // all 4 quadrant-lanes of a cg now hold the full 8-ch sums; each writes 2
    const int c0 = cg * 8 + sub * 2;
    obuf[(c0 + 0) * NBIN + bb] = acc[sub * 2 + 0];
    obuf[(c0 + 1) * NBIN + bb] = acc[sub * 2 + 1];
  }
  __syncthreads();

  // coalesced write-out: this half's 6272 floats are contiguous in out
  fx4* o4 = (fx4*)(out + (size_t)r * (NBIN * C_CH) + (size_t)p * (CHALF * NBIN));
  const fx4* ob4 = (const fx4*)obuf;
  for (int i = t; i < CHALF * NBIN / 4; i += 512)
    __builtin_nontemporal_store(ob4[i], o4 + i);
}

// ---------------------------------------------------------------------------
// Fallback: direct NCHW f32 gather (used only if workspace is too small).
// ---------------------------------------------------------------------------
__global__ __launch_bounds__(256) void roi_gather_nchw(
    const float* __restrict__ f0, const float* __restrict__ f1,
    const float* __restrict__ f2, const float* __restrict__ f3,
    const float* __restrict__ props0, const float* __restrict__ props1,
    float* __restrict__ out) {
  __shared__ float obuf[NBIN * C_CH];
  __shared__ int s_o0[2][14], s_o1[2][14];
  __shared__ float s_w0[2][14], s_w1[2][14];

  const int r = blockIdx.x;
  const int t = threadIdx.x;
  const int b = (r >= 512) ? 1 : 0;
  const float* pr = (b ? props1 : props0) + (r & 511) * 4;
  const float x1 = pr[0], y1 = pr[1], x2 = pr[2], y2 = pr[3];
  const float size = sqrtf((x2 - x1 + 1.0f) * (y2 - y1 + 1.0f));
  float lv = floorf(4.0f + log2f(size / 224.0f + 1e-6f));
  lv = fminf(fmaxf(lv, 2.0f), 5.0f) - 2.0f;
  const int lvl = (int)lv;
  const int Htab[4] = {200, 100, 50, 25};
  const float stab[4] = {0.25f, 0.125f, 0.0625f, 0.03125f};
  const int H = Htab[lvl];
  const int W = H;
  const float sc = stab[lvl];
  const float* fl = (lvl == 0) ? f0 : (lvl == 1) ? f1 : (lvl == 2) ? f2 : f3;
  const float rx1 = x1 * sc, ry1 = y1 * sc;
  const float roi_w = fmaxf(x2 * sc - rx1, 1.0f);
  const float roi_h = fmaxf(y2 * sc - ry1, 1.0f);
  const float bw = roi_w / 7.0f, bh = roi_h / 7.0f;
  if (t < 28) {
    const int axis = t / 14;
    const int k = t % 14;
    const float off = ((float)k + 0.5f) * 0.5f;
    const float v = axis ? (rx1 + off * bw) : (ry1 + off * bh);
    const int isz = H;
    const bool valid = (v >= -1.0f) && (v <= (float)isz);
    const float v0 = fmaxf(v, 0.0f);
    int lo = (int)floorf(v0);
    const bool edge = (lo >= isz - 1);
    lo = edge ? isz - 1 : lo;
    const int hi = edge ? isz - 1 : lo + 1;
    const float fr = edge ? 0.0f : (v0 - (float)lo);
    const int mul = axis ? 1 : W;
    s_o0[axis][k] = lo * mul;
    s_o1[axis][k] = hi * mul;
    s_w1[axis][k] = valid ? fr : 0.0f;
    s_w0[axis][k] = valid ? (1.0f - fr) : 0.0f;
  }
  __syncthreads();
  const int wv = t >> 6;
  const int ln = t & 63;
  const size_t HWp = (size_t)H * W;
  const float* base = fl + ((size_t)b * C_CH + ln * 4) * HWp;
  for (int bb = wv; bb < NBIN; bb += 4) {
    const int ph = bb / 7, pw = bb - ph * 7;
    float4 acc = make_float4(0.f, 0.f, 0.f, 0.f);
    for (int s1 = 0; s1 < 2; ++s1) {
      const int sy = 2 * ph + s1;
      const int yo0 = s_o0[0][sy], yo1 = s_o1[0][sy];
      const float wy0 = s_w0[0][sy], wy1 = s_w1[0][sy];
      for (int s2 = 0; s2 < 2; ++s2) {
        const int sx = 2 * pw + s2;
        const int xo0 = s_o0[1][sx], xo1 = s_o1[1][sx];
        const float w00 = wy0 * s_w0[1][sx], w01 = wy0 * s_w1[1][sx];
        const float w10 = wy1 * s_w0[1][sx], w11 = wy1 * s_w1[1][sx];
        float e[4];
        for (int j = 0; j < 4; ++j) {
          e[j] = w00 * base[j * HWp + yo0 + xo0] + w01 * base[j * HWp + yo0 + xo1] +
                 w10 * base[j * HWp + yo1 + xo0] + w11 * base[j * HWp + yo1 + xo1];
        }
        acc.x += e[0]; acc.y += e[1]; acc.z += e[2]; acc.w += e[3];
      }
    }
    const int c4 = ln * 4;
    obuf[(c4 + 0) * NBIN + bb] = acc.x * 0.25f;
    obuf[(c4 + 1) * NBIN + bb] = acc.y * 0.25f;
    obuf[(c4 + 2) * NBIN + bb] = acc.z * 0.25f;
    obuf[(c4 + 3) * NBIN + bb] = acc.w * 0.25f;
  }
  __syncthreads();
  float4* o4 = (float4*)(out + (size_t)r * (NBIN * C_CH));
  const float4* ob4 = (const float4*)obuf;
  for (int i = t; i < NBIN * C_CH / 4; i += 256) o4[i] = ob4[i];
}

// ---------------------------------------------------------------------------
extern "C" void kernel_launch(void* const* d_in, const int* in_sizes, int n_in,
                              void* d_out, int out_size, void* d_ws, size_t ws_size,
                              hipStream_t stream) {
  const float* f0 = (const float*)d_in[0];
  const float* f1 = (const float*)d_in[1];
  const float* f2 = (const float*)d_in[2];
  const float* f3 = (const float*)d_in[3];
  // d_in[4] (feat4, 13x13) unused by reference
  const float* p0 = (const float*)d_in[5];
  const float* p1 = (const float*)d_in[6];
  float* out = (float*)d_out;
  unsigned short* ws = (unsigned short*)d_ws;

  const int HWs[4] = {200 * 200, 100 * 100, 50 * 50, 25 * 25};
  size_t off[4];
  size_t acc = 0;
  for (int l = 0; l < 4; ++l) {
    off[l] = acc;
    acc += (size_t)2 * C_CH * HWs[l];
  }
  const size_t need_bytes = acc * sizeof(unsigned short);  // ~54.4 MB

  if (ws_size >= need_bytes) {
    TArgs a;
    a.src[0] = f0; a.src[1] = f1; a.src[2] = f2; a.src[3] = f3;
    int cum = 0;
    for (int l = 0; l < 4; ++l) {
      a.dst[l] = ws + off[l];
      a.hw[l] = HWs[l];
      a.tilesx[l] = (HWs[l] + 63) / 64;
      a.tbase[l] = cum;
      cum += a.tilesx[l] * 4 * 2;
    }
    a.tbase[4] = cum;
    a.total = cum;  // 6656
    const int nblocks = (cum < 2048) ? cum : 2048;
    conv_nhwc_bf16<<<nblocks, 256, 0, stream>>>(a);
    roi_gather_bf16<<<2048, 512, 0, stream>>>(a.dst[0], a.dst[1], a.dst[2], a.dst[3],
                                              p0, p1, out);
  } else {
    roi_gather_nchw<<<1024, 256, 0, stream>>>(f0, f1, f2, f3, p0, p1, out);
  }
}

// Round 2
// 187.661 us; speedup vs baseline: 1.0084x; 1.0084x over previous
//
#include <hip/hip_runtime.h>
#include <math.h>

#define C_CH 256
#define RESO 7
#define NBIN 49   // 7*7
#define CHALF 128 // channels per gather block

typedef float fx4 __attribute__((ext_vector_type(4)));
typedef unsigned int ux2 __attribute__((ext_vector_type(2)));

// f32 -> bf16, round-to-nearest-even
__device__ __forceinline__ unsigned short f2bf(float f) {
  unsigned int u = __float_as_uint(f);
  u = (u + 0x7fffu + ((u >> 16) & 1u)) >> 16;
  return (unsigned short)u;
}
__device__ __forceinline__ float bf_lo(unsigned int u) { return __uint_as_float(u << 16); }
__device__ __forceinline__ float bf_hi(unsigned int u) { return __uint_as_float(u & 0xffff0000u); }

// ---------------------------------------------------------------------------
// Merged NCHW(f32) -> NHWC(bf16), all 4 levels, ONE persistent dispatch.
// (unchanged — measured near its streaming roofline)
// ---------------------------------------------------------------------------
struct TArgs {
  const float* src[4];
  unsigned short* dst[4];
  int hw[4];
  int tilesx[4];  // ceil(hw/64)
  int tbase[5];   // cumulative tiles per level (tilesx*4*2)
  int total;
};

__device__ __forceinline__ void decode_tile(const TArgs& a, int T, int& l, int& hw0,
                                            int& c0, int& n, int& HW) {
  int ll = 0;
  if (T >= a.tbase[1]) ll = 1;
  if (T >= a.tbase[2]) ll = 2;
  if (T >= a.tbase[3]) ll = 3;
  const int idx = T - a.tbase[ll];
  const int txs = a.tilesx[ll];
  const int tx = idx % txs;
  const int rem = idx / txs;
  l = ll;
  hw0 = tx * 64;
  c0 = (rem & 3) * 64;
  n = rem >> 2;
  HW = a.hw[ll];
}

__device__ __forceinline__ void load_tile(const TArgs& a, int l, int hw0, int c0, int n,
                                          int HW, int lane16, int row16, fx4 v[4]) {
  const float* s = a.src[l] + (size_t)n * C_CH * HW;
  if (((HW & 3) == 0) && (hw0 + 64 <= HW)) {
#pragma unroll
    for (int i = 0; i < 4; ++i) {
      const int c_l = row16 + 16 * i;
      v[i] = __builtin_nontemporal_load(
          (const fx4*)(s + (size_t)(c0 + c_l) * HW + hw0 + lane16 * 4));
    }
  } else {
#pragma unroll
    for (int i = 0; i < 4; ++i) {
      const int c_l = row16 + 16 * i;
      const float* row = s + (size_t)(c0 + c_l) * HW;
#pragma unroll
      for (int k = 0; k < 4; ++k) {
        const int hw = hw0 + lane16 * 4 + k;
        v[i][k] = (hw < HW) ? row[hw] : 0.0f;
      }
    }
  }
}

__global__ __launch_bounds__(256) void conv_nhwc_bf16(TArgs a) {
  __shared__ float tile[64][65];
  const int t = threadIdx.x;
  const int lane16 = t & 15;
  const int row16 = t >> 4;
  const int stride = gridDim.x;

  int T = blockIdx.x;
  int l0, hw00, c00, n0, HW0;
  decode_tile(a, T, l0, hw00, c00, n0, HW0);
  fx4 v[4];
  load_tile(a, l0, hw00, c00, n0, HW0, lane16, row16, v);

  while (true) {
    __syncthreads();  // previous store phase done reading LDS
#pragma unroll
    for (int i = 0; i < 4; ++i) {
      const int c_l = row16 + 16 * i;
      tile[c_l][lane16 * 4 + 0] = v[i][0];
      tile[c_l][lane16 * 4 + 1] = v[i][1];
      tile[c_l][lane16 * 4 + 2] = v[i][2];
      tile[c_l][lane16 * 4 + 3] = v[i][3];
    }

    // prefetch next tile BEFORE the barrier -> loads overlap store phase
    const int Tn = T + stride;
    const bool more = Tn < a.total;
    int l1, hw01, c01, n1, HW1;
    fx4 w[4];
    if (more) {
      decode_tile(a, Tn, l1, hw01, c01, n1, HW1);
      load_tile(a, l1, hw01, c01, n1, HW1, lane16, row16, w);
    }
    __syncthreads();

    // store phase for tile T
    unsigned short* d = a.dst[l0] + (size_t)n0 * HW0 * C_CH;
#pragma unroll
    for (int i = 0; i < 4; ++i) {
      const int hw_l = row16 + 16 * i;
      const int hww = hw00 + hw_l;
      if (hww < HW0) {
        const int c4 = lane16 * 4;
        ux2 p;
        p.x = (unsigned int)f2bf(tile[c4 + 0][hw_l]) |
              ((unsigned int)f2bf(tile[c4 + 1][hw_l]) << 16);
        p.y = (unsigned int)f2bf(tile[c4 + 2][hw_l]) |
              ((unsigned int)f2bf(tile[c4 + 3][hw_l]) << 16);
        *(ux2*)(d + (size_t)hww * C_CH + c00 + c4) = p;
      }
    }

    if (!more) break;
    T = Tn;
    l0 = l1; hw00 = hw01; c00 = c01; n0 = n1; HW0 = HW1;
#pragma unroll
    for (int i = 0; i < 4; ++i) v[i] = w[i];
  }
}

// ---------------------------------------------------------------------------
// RoIAlign gather, bf16 NHWC.  2048 blocks x 256 thr: block = (ROI, ch-half).
// SHUFFLE-FREE restructure: each lane owns one (bin, 8-channel-group) task
// and performs the complete 2x2-sample x 2x2-tap bilinear sum in registers
// (16 uint4 loads, 0 cross-lane ops).  Task id = t + 256*i, bb = id>>4,
// cg = id&15 -> 16 consecutive lanes read 256 B contiguous per tap, same
// coalescing as before, but ~9x fewer wave-level DS ops per ROI (the old
// structure spent 16 shfl_xor per bin per lane combining quadrants).
// ---------------------------------------------------------------------------
__global__ __launch_bounds__(256) void roi_gather_bf16(
    const unsigned short* __restrict__ f0, const unsigned short* __restrict__ f1,
    const unsigned short* __restrict__ f2, const unsigned short* __restrict__ f3,
    const float* __restrict__ props0, const float* __restrict__ props1,
    float* __restrict__ out) {
  __shared__ float obuf[CHALF * NBIN];      // c-major: obuf[c_local*49 + bin]
  __shared__ int s_o0[2][14], s_o1[2][14];  // pre-scaled lo/hi offsets (0=y,1=x)
  __shared__ float s_w0[2][14], s_w1[2][14];

  const int bid = blockIdx.x;
  const int r = bid >> 1;   // ROI index 0..1023
  const int p = bid & 1;    // channel half 0..1
  const int t = threadIdx.x;
  const int b = (r >= 512) ? 1 : 0;
  const float* pr = (b ? props1 : props0) + (r & 511) * 4;
  const float x1 = pr[0], y1 = pr[1], x2 = pr[2], y2 = pr[3];

  // level assignment (match numpy f32 math exactly)
  const float size = sqrtf((x2 - x1 + 1.0f) * (y2 - y1 + 1.0f));
  float lv = floorf(4.0f + log2f(size / 224.0f + 1e-6f));
  lv = fminf(fmaxf(lv, 2.0f), 5.0f) - 2.0f;
  const int lvl = (int)lv;

  const int Htab[4] = {200, 100, 50, 25};
  const float stab[4] = {0.25f, 0.125f, 0.0625f, 0.03125f};
  const int H = Htab[lvl];
  const int W = H;
  const float sc = stab[lvl];
  const unsigned short* fl = (lvl == 0) ? f0 : (lvl == 1) ? f1 : (lvl == 2) ? f2 : f3;

  const float rx1 = x1 * sc, ry1 = y1 * sc;
  const float roi_w = fmaxf(x2 * sc - rx1, 1.0f);
  const float roi_h = fmaxf(y2 * sc - ry1, 1.0f);
  const float bw = roi_w / 7.0f, bh = roi_h / 7.0f;

  if (t < 28) {
    const int axis = t / 14;  // 0 = y, 1 = x
    const int k = t % 14;
    const float off = ((float)k + 0.5f) * 0.5f;
    const float v = axis ? (rx1 + off * bw) : (ry1 + off * bh);
    const int isz = H;
    const bool valid = (v >= -1.0f) && (v <= (float)isz);
    const float v0 = fmaxf(v, 0.0f);
    int lo = (int)floorf(v0);
    const bool edge = (lo >= isz - 1);
    lo = edge ? isz - 1 : lo;
    const int hi = edge ? isz - 1 : lo + 1;
    const float fr = edge ? 0.0f : (v0 - (float)lo);
    const int mul = axis ? C_CH : W * C_CH;
    // fold the 2x2-sample mean (0.25) into the y-axis weights
    const float wsc = axis ? 1.0f : 0.25f;
    s_o0[axis][k] = lo * mul;
    s_o1[axis][k] = hi * mul;
    s_w1[axis][k] = valid ? fr * wsc : 0.0f;
    s_w0[axis][k] = valid ? (1.0f - fr) * wsc : 0.0f;
  }
  __syncthreads();

  const size_t HWp = (size_t)H * W;
  const unsigned short* baseR = fl + (size_t)b * HWp * C_CH + p * CHALF;

  // 49 bins x 16 channel-groups = 784 tasks, grid-stride over 256 threads
  for (int ti = t; ti < NBIN * 16; ti += 256) {
    const int bb = ti >> 4;         // bin 0..48
    const int cg = ti & 15;         // channel group of 8 within this half
    const int ph = bb / 7, pw = bb - ph * 7;
    const unsigned short* bp = baseR + cg * 8;
    float acc[8] = {0.f, 0.f, 0.f, 0.f, 0.f, 0.f, 0.f, 0.f};
#pragma unroll
    for (int s1 = 0; s1 < 2; ++s1) {
      const int sy = 2 * ph + s1;
      const int yo0 = s_o0[0][sy], yo1 = s_o1[0][sy];
      const float wy0 = s_w0[0][sy], wy1 = s_w1[0][sy];  // 0.25 folded in
#pragma unroll
      for (int s2 = 0; s2 < 2; ++s2) {
        const int sx = 2 * pw + s2;
        const int xo0 = s_o0[1][sx], xo1 = s_o1[1][sx];
        const float wx0 = s_w0[1][sx], wx1 = s_w1[1][sx];
        const uint4 q00 = *(const uint4*)(bp + yo0 + xo0);
        const uint4 q01 = *(const uint4*)(bp + yo0 + xo1);
        const uint4 q10 = *(const uint4*)(bp + yo1 + xo0);
        const uint4 q11 = *(const uint4*)(bp + yo1 + xo1);
        const float w00 = wy0 * wx0, w01 = wy0 * wx1;
        const float w10 = wy1 * wx0, w11 = wy1 * wx1;
        acc[0] = fmaf(bf_lo(q00.x), w00, acc[0]);
        acc[1] = fmaf(bf_hi(q00.x), w00, acc[1]);
        acc[2] = fmaf(bf_lo(q00.y), w00, acc[2]);
        acc[3] = fmaf(bf_hi(q00.y), w00, acc[3]);
        acc[4] = fmaf(bf_lo(q00.z), w00, acc[4]);
        acc[5] = fmaf(bf_hi(q00.z), w00, acc[5]);
        acc[6] = fmaf(bf_lo(q00.w), w00, acc[6]);
        acc[7] = fmaf(bf_hi(q00.w), w00, acc[7]);
        acc[0] = fmaf(bf_lo(q01.x), w01, acc[0]);
        acc[1] = fmaf(bf_hi(q01.x), w01, acc[1]);
        acc[2] = fmaf(bf_lo(q01.y), w01, acc[2]);
        acc[3] = fmaf(bf_hi(q01.y), w01, acc[3]);
        acc[4] = fmaf(bf_lo(q01.z), w01, acc[4]);
        acc[5] = fmaf(bf_hi(q01.z), w01, acc[5]);
        acc[6] = fmaf(bf_lo(q01.w), w01, acc[6]);
        acc[7] = fmaf(bf_hi(q01.w), w01, acc[7]);
        acc[0] = fmaf(bf_lo(q10.x), w10, acc[0]);
        acc[1] = fmaf(bf_hi(q10.x), w10, acc[1]);
        acc[2] = fmaf(bf_lo(q10.y), w10, acc[2]);
        acc[3] = fmaf(bf_hi(q10.y), w10, acc[3]);
        acc[4] = fmaf(bf_lo(q10.z), w10, acc[4]);
        acc[5] = fmaf(bf_hi(q10.z), w10, acc[5]);
        acc[6] = fmaf(bf_lo(q10.w), w10, acc[6]);
        acc[7] = fmaf(bf_hi(q10.w), w10, acc[7]);
        acc[0] = fmaf(bf_lo(q11.x), w11, acc[0]);
        acc[1] = fmaf(bf_hi(q11.x), w11, acc[1]);
        acc[2] = fmaf(bf_lo(q11.y), w11, acc[2]);
        acc[3] = fmaf(bf_hi(q11.y), w11, acc[3]);
        acc[4] = fmaf(bf_lo(q11.z), w11, acc[4]);
        acc[5] = fmaf(bf_hi(q11.z), w11, acc[5]);
        acc[6] = fmaf(bf_lo(q11.w), w11, acc[6]);
        acc[7] = fmaf(bf_hi(q11.w), w11, acc[7]);
      }
    }
    const int c0 = cg * 8;
#pragma unroll
    for (int k = 0; k < 8; ++k)
      obuf[(c0 + k) * NBIN + bb] = acc[k];
  }
  __syncthreads();

  // coalesced write-out: this half's 6272 floats are contiguous in out
  fx4* o4 = (fx4*)(out + (size_t)r * (NBIN * C_CH) + (size_t)p * (CHALF * NBIN));
  const fx4* ob4 = (const fx4*)obuf;
  for (int i = t; i < CHALF * NBIN / 4; i += 256)
    __builtin_nontemporal_store(ob4[i], o4 + i);
}

// ---------------------------------------------------------------------------
// Fallback: direct NCHW f32 gather (used only if workspace is too small).
// ---------------------------------------------------------------------------
__global__ __launch_bounds__(256) void roi_gather_nchw(
    const float* __restrict__ f0, const float* __restrict__ f1,
    const float* __restrict__ f2, const float* __restrict__ f3,
    const float* __restrict__ props0, const float* __restrict__ props1,
    float* __restrict__ out) {
  __shared__ float obuf[NBIN * C_CH];
  __shared__ int s_o0[2][14], s_o1[2][14];
  __shared__ float s_w0[2][14], s_w1[2][14];

  const int r = blockIdx.x;
  const int t = threadIdx.x;
  const int b = (r >= 512) ? 1 : 0;
  const float* pr = (b ? props1 : props0) + (r & 511) * 4;
  const float x1 = pr[0], y1 = pr[1], x2 = pr[2], y2 = pr[3];
  const float size = sqrtf((x2 - x1 + 1.0f) * (y2 - y1 + 1.0f));
  float lv = floorf(4.0f + log2f(size / 224.0f + 1e-6f));
  lv = fminf(fmaxf(lv, 2.0f), 5.0f) - 2.0f;
  const int lvl = (int)lv;
  const int Htab[4] = {200, 100, 50, 25};
  const float stab[4] = {0.25f, 0.125f, 0.0625f, 0.03125f};
  const int H = Htab[lvl];
  const int W = H;
  const float sc = stab[lvl];
  const float* fl = (lvl == 0) ? f0 : (lvl == 1) ? f1 : (lvl == 2) ? f2 : f3;
  const float rx1 = x1 * sc, ry1 = y1 * sc;
  const float roi_w = fmaxf(x2 * sc - rx1, 1.0f);
  const float roi_h = fmaxf(y2 * sc - ry1, 1.0f);
  const float bw = roi_w / 7.0f, bh = roi_h / 7.0f;
  if (t < 28) {
    const int axis = t / 14;
    const int k = t % 14;
    const float off = ((float)k + 0.5f) * 0.5f;
    const float v = axis ? (rx1 + off * bw) : (ry1 + off * bh);
    const int isz = H;
    const bool valid = (v >= -1.0f) && (v <= (float)isz);
    const float v0 = fmaxf(v, 0.0f);
    int lo = (int)floorf(v0);
    const bool edge = (lo >= isz - 1);
    lo = edge ? isz - 1 : lo;
    const int hi = edge ? isz - 1 : lo + 1;
    const float fr = edge ? 0.0f : (v0 - (float)lo);
    const int mul = axis ? 1 : W;
    s_o0[axis][k] = lo * mul;
    s_o1[axis][k] = hi * mul;
    s_w1[axis][k] = valid ? fr : 0.0f;
    s_w0[axis][k] = valid ? (1.0f - fr) : 0.0f;
  }
  __syncthreads();
  const int wv = t >> 6;
  const int ln = t & 63;
  const size_t HWp = (size_t)H * W;
  const float* base = fl + ((size_t)b * C_CH + ln * 4) * HWp;
  for (int bb = wv; bb < NBIN; bb += 4) {
    const int ph = bb / 7, pw = bb - ph * 7;
    float4 acc = make_float4(0.f, 0.f, 0.f, 0.f);
    for (int s1 = 0; s1 < 2; ++s1) {
      const int sy = 2 * ph + s1;
      const int yo0 = s_o0[0][sy], yo1 = s_o1[0][sy];
      const float wy0 = s_w0[0][sy], wy1 = s_w1[0][sy];
      for (int s2 = 0; s2 < 2; ++s2) {
        const int sx = 2 * pw + s2;
        const int xo0 = s_o0[1][sx], xo1 = s_o1[1][sx];
        const float w00 = wy0 * s_w0[1][sx], w01 = wy0 * s_w1[1][sx];
        const float w10 = wy1 * s_w0[1][sx], w11 = wy1 * s_w1[1][sx];
        float e[4];
        for (int j = 0; j < 4; ++j) {
          e[j] = w00 * base[j * HWp + yo0 + xo0] + w01 * base[j * HWp + yo0 + xo1] +
                 w10 * base[j * HWp + yo1 + xo0] + w11 * base[j * HWp + yo1 + xo1];
        }
        acc.x += e[0]; acc.y += e[1]; acc.z += e[2]; acc.w += e[3];
      }
    }
    const int c4 = ln * 4;
    obuf[(c4 + 0) * NBIN + bb] = acc.x * 0.25f;
    obuf[(c4 + 1) * NBIN + bb] = acc.y * 0.25f;
    obuf[(c4 + 2) * NBIN + bb] = acc.z * 0.25f;
    obuf[(c4 + 3) * NBIN + bb] = acc.w * 0.25f;
  }
  __syncthreads();
  float4* o4 = (float4*)(out + (size_t)r * (NBIN * C_CH));
  const float4* ob4 = (const float4*)obuf;
  for (int i = t; i < NBIN * C_CH / 4; i += 256) o4[i] = ob4[i];
}

// ---------------------------------------------------------------------------
extern "C" void kernel_launch(void* const* d_in, const int* in_sizes, int n_in,
                              void* d_out, int out_size, void* d_ws, size_t ws_size,
                              hipStream_t stream) {
  const float* f0 = (const float*)d_in[0];
  const float* f1 = (const float*)d_in[1];
  const float* f2 = (const float*)d_in[2];
  const float* f3 = (const float*)d_in[3];
  // d_in[4] (feat4, 13x13) unused by reference
  const float* p0 = (const float*)d_in[5];
  const float* p1 = (const float*)d_in[6];
  float* out = (float*)d_out;
  unsigned short* ws = (unsigned short*)d_ws;

  const int HWs[4] = {200 * 200, 100 * 100, 50 * 50, 25 * 25};
  size_t off[4];
  size_t acc = 0;
  for (int l = 0; l < 4; ++l) {
    off[l] = acc;
    acc += (size_t)2 * C_CH * HWs[l];
  }
  const size_t need_bytes = acc * sizeof(unsigned short);  // ~54.4 MB

  if (ws_size >= need_bytes) {
    TArgs a;
    a.src[0] = f0; a.src[1] = f1; a.src[2] = f2; a.src[3] = f3;
    int cum = 0;
    for (int l = 0; l < 4; ++l) {
      a.dst[l] = ws + off[l];
      a.hw[l] = HWs[l];
      a.tilesx[l] = (HWs[l] + 63) / 64;
      a.tbase[l] = cum;
      cum += a.tilesx[l] * 4 * 2;
    }
    a.tbase[4] = cum;
    a.total = cum;  // 6656
    const int nblocks = (cum < 2048) ? cum : 2048;
    conv_nhwc_bf16<<<nblocks, 256, 0, stream>>>(a);
    roi_gather_bf16<<<2048, 256, 0, stream>>>(a.dst[0], a.dst[1], a.dst[2], a.dst[3],
                                              p0, p1, out);
  } else {
    roi_gather_nchw<<<1024, 256, 0, stream>>>(f0, f1, f2, f3, p0, p1, out);
  }
}